// Round 3
// baseline (356.733 us; speedup 1.0000x reference)
//
#include <hip/hip_runtime.h>
#include <math.h>

#define B_  4
#define T_  16
#define C_  64
#define CQ_ 8
#define HW_ 9216          // 96*96
#define NCHUNK_ 288       // HW_/32

// ws layout (floats): WT[2][64][32] @ 0 ; partE @ 4096 ; heat @ 4096 + B*288*256

// ---------------------------------------------------------------------------
// k_prep: transpose conv weights so each ci's row (8 cq x 3 taps = 24 floats)
// is contiguous (stride 32) -> enables scalar (s_load) fetches in k_energy.
// ---------------------------------------------------------------------------
__global__ __launch_bounds__(256)
void k_prep(const float* __restrict__ wq, const float* __restrict__ wk,
            float* __restrict__ WT) {
  for (int j = threadIdx.x; j < CQ_ * C_ * 3; j += 256) {
    int ci = j / 24, r = j % 24;      // r = cqi*3 + d
    int cqi = r / 3, d = r % 3;
    WT[ci * 32 + r]        = wq[(cqi * C_ + ci) * 3 + d];
    WT[2048 + ci * 32 + r] = wk[(cqi * C_ + ci) * 3 + d];
  }
}

// ---------------------------------------------------------------------------
// k_energy: partial energies. grid (288, 4), block 512 = (t=16 x g=32).
// Conv weights come from global via wave-uniform (scalar) loads — no LDS.
// ---------------------------------------------------------------------------
__global__ __launch_bounds__(512, 4)
void k_energy(const float* __restrict__ x, const float* __restrict__ WT,
              const float* __restrict__ bq, const float* __restrict__ bk,
              float* __restrict__ partE) {
  // Q/K layout: [g][t][12], per-g stride 196 (breaks 16*12%32==0 bank cycle)
  __shared__ __attribute__((aligned(16))) float QK[2 * 32 * 196];
  __shared__ float Etmp[256];

  const int b   = blockIdx.y;
  const int hw0 = blockIdx.x * 32;
  const int tid = threadIdx.x;
  const int t = tid >> 5;   // 0..15
  const int g = tid & 31;   // 0..31
  const float* xb  = x + (size_t)(b * T_ * C_) * HW_ + hw0 + g;
  const float* wqt = WT;           // [ci*32 + cqi*3 + d]
  const float* wkt = WT + 2048;

  float qa[CQ_], ka[CQ_];
#pragma unroll
  for (int j = 0; j < CQ_; ++j) { qa[j] = 0.f; ka[j] = 0.f; }

#pragma unroll 2
  for (int ci = 0; ci < C_; ++ci) {
    float xm = 0.f, xp = 0.f;
    if (t > 0)      xm = xb[(size_t)((t - 1) * C_ + ci) * HW_];
    float x0 =           xb[(size_t)(t * C_ + ci) * HW_];
    if (t < T_ - 1) xp = xb[(size_t)((t + 1) * C_ + ci) * HW_];
    const float* wq_r = &wqt[ci * 32];
    const float* wk_r = &wkt[ci * 32];
#pragma unroll
    for (int j = 0; j < CQ_; ++j) {
      qa[j] += wq_r[j * 3 + 0] * xm + wq_r[j * 3 + 1] * x0 + wq_r[j * 3 + 2] * xp;
      ka[j] += wk_r[j * 3 + 0] * xm + wk_r[j * 3 + 1] * x0 + wk_r[j * 3 + 2] * xp;
    }
  }
#pragma unroll
  for (int j = 0; j < CQ_; ++j) { qa[j] += bq[j]; ka[j] += bk[j]; }

  float* Qs = &QK[0];
  float* Ks = &QK[32 * 196];
#pragma unroll
  for (int j = 0; j < CQ_; ++j) {
    Qs[g * 196 + t * 12 + j] = qa[j];
    Ks[g * 196 + t * 12 + j] = ka[j];
  }
  __syncthreads();

  // E-dot: thread -> (h, tt, ss); h splits the 32 g's in half.
  const int h  = tid >> 8;
  const int tt = (tid >> 4) & 15;
  const int ss = tid & 15;
  float e = 0.f;
  for (int gg = h * 16; gg < h * 16 + 16; ++gg) {
    const float4 q0 = *(const float4*)&Qs[gg * 196 + tt * 12];
    const float4 q1 = *(const float4*)&Qs[gg * 196 + tt * 12 + 4];
    const float4 k0 = *(const float4*)&Ks[gg * 196 + ss * 12];
    const float4 k1 = *(const float4*)&Ks[gg * 196 + ss * 12 + 4];
    e += q0.x * k0.x + q0.y * k0.y + q0.z * k0.z + q0.w * k0.w
       + q1.x * k1.x + q1.y * k1.y + q1.z * k1.z + q1.w * k1.w;
  }
  if (h == 1) Etmp[tt * 16 + ss] = e;
  __syncthreads();
  if (h == 0) {
    e += Etmp[tt * 16 + ss];
    partE[((size_t)(b * NCHUNK_ + blockIdx.x)) * 256 + tt * 16 + ss] = e;
  }
}

// ---------------------------------------------------------------------------
// k_softmax: reduce 288 partials and softmax over s. grid 4, block 256.
// ---------------------------------------------------------------------------
__global__ __launch_bounds__(256)
void k_softmax(const float* __restrict__ partE, float* __restrict__ heat) {
  const int b = blockIdx.x;
  const int tid = threadIdx.x;
  float e = 0.f;
  for (int ch = 0; ch < NCHUNK_; ++ch)
    e += partE[((size_t)(b * NCHUNK_ + ch)) * 256 + tid];
  float mx = e;
#pragma unroll
  for (int m = 1; m < 16; m <<= 1) mx = fmaxf(mx, __shfl_xor(mx, m, 64));
  float ex = expf(e - mx);
  float sm = ex;
#pragma unroll
  for (int m = 1; m < 16; m <<= 1) sm += __shfl_xor(sm, m, 64);
  heat[b * 256 + tid] = ex / sm;
}

// ---------------------------------------------------------------------------
// k_mix: fused tmix + cmix + residual, s-split into two staged phases.
//   out[b,t,c,g] = gamma*( sum_ci Wv[c,ci] * sum_s heat[t,s] x[b,s,ci,g]
//                          + bv[c] ) + x[b,t,c,g]
// grid (576, 4), block 256 = (t=16 x g=16). Each phase stages 8 s-planes of
// x as xs[s'][g][ci] (stride 68; 2-way banks = free); xh[64] accumulates
// across phases. After phase 1 the s=8..15 tile stays in LDS, so waves with
// t>=8 (wave-uniform) take their residual from LDS instead of global.
// LDS 35.8 KB -> 4 blocks/CU; __launch_bounds__(256,4) caps VGPR at 128
// -> 16 waves/CU (2x round-2 occupancy).
// ---------------------------------------------------------------------------
__global__ __launch_bounds__(256, 4)
void k_mix(const float* __restrict__ x, const float* __restrict__ heat,
           const float* __restrict__ wv, const float* __restrict__ bv,
           const float* __restrict__ gam, float* __restrict__ out) {
  __shared__ __attribute__((aligned(16))) float xs[8 * 16 * 68]; // [s'][g][ci]
  __shared__ float hs[256];

  const int b   = blockIdx.y;
  const int hw0 = blockIdx.x * 16;
  const int tid = threadIdx.x;

  hs[tid] = heat[b * 256 + tid];

  const float* xbase = x + (size_t)(b * T_ * C_) * HW_ + hw0;
  const int t = tid >> 4;   // 0..15
  const int g = tid & 15;   // 0..15

  float xh[C_];
#pragma unroll
  for (int ci = 0; ci < C_; ++ci) xh[ci] = 0.f;

#pragma unroll
  for (int p = 0; p < 2; ++p) {
    __syncthreads();   // protect xs (phase 0: hs write; phase 1: reuse)
    // stage x[b, p*8..p*8+7, :, hw0:hw0+16] -> xs[s'][g][ci]
#pragma unroll
    for (int kk = 0; kk < 8; ++kk) {
      int slot = kk * 256 + tid;        // 0..2047
      int row  = slot >> 2;             // s'*64 + ci
      int quad = slot & 3;              // which 4 g's
      int sp = row >> 6, ci = row & 63;
      float4 v = *(const float4*)(xbase +
                  (size_t)((p * 8 + sp) * C_ + ci) * HW_ + quad * 4);
      float* dst = &xs[(sp * 16 + quad * 4) * 68 + ci];
      dst[0 * 68] = v.x;
      dst[1 * 68] = v.y;
      dst[2 * 68] = v.z;
      dst[3 * 68] = v.w;
    }
    __syncthreads();

    // xh[ci] += sum_{s'} h[p*8+s'] * x[p*8+s', ci, g]
#pragma unroll
    for (int cq = 0; cq < 16; ++cq) {
      float ax = 0.f, ay = 0.f, az = 0.f, aw = 0.f;
#pragma unroll
      for (int sp = 0; sp < 8; ++sp) {
        const float h = hs[t * 16 + p * 8 + sp];
        const float4 v = *(const float4*)&xs[(sp * 16 + g) * 68 + cq * 4];
        ax += h * v.x; ay += h * v.y; az += h * v.z; aw += h * v.w;
      }
      xh[cq * 4 + 0] += ax; xh[cq * 4 + 1] += ay;
      xh[cq * 4 + 2] += az; xh[cq * 4 + 3] += aw;
    }
  }

  // c-mix with scalar-loaded weights + bias + residual.
  // xs still holds s=8..15 -> waves with t>=8 read residual from LDS.
  const float gamma = gam[0];
  float* op = out + ((size_t)(b * T_ + t) * C_) * HW_ + hw0 + g;
  if (t >= 8) {
    const float* rrow = &xs[((t - 8) * 16 + g) * 68];
    for (int c = 0; c < C_; ++c) {
      const float* wr = wv + c * C_;     // wave-uniform -> s_load
      float o = 0.f;
#pragma unroll
      for (int ci = 0; ci < C_; ++ci) o += wr[ci] * xh[ci];
      op[(size_t)c * HW_] = gamma * (o + bv[c]) + rrow[c];
    }
  } else {
    const float* xr = x + ((size_t)(b * T_ + t) * C_) * HW_ + hw0 + g;
    for (int c = 0; c < C_; ++c) {
      const float* wr = wv + c * C_;
      float o = 0.f;
#pragma unroll
      for (int ci = 0; ci < C_; ++ci) o += wr[ci] * xh[ci];
      op[(size_t)c * HW_] = gamma * (o + bv[c]) + xr[(size_t)c * HW_];
    }
  }
}

// ---------------------------------------------------------------------------
extern "C" void kernel_launch(void* const* d_in, const int* in_sizes, int n_in,
                              void* d_out, int out_size, void* d_ws, size_t ws_size,
                              hipStream_t stream) {
  const float* x   = (const float*)d_in[0];
  const float* wq  = (const float*)d_in[1];
  const float* bq  = (const float*)d_in[2];
  const float* wk  = (const float*)d_in[3];
  const float* bk  = (const float*)d_in[4];
  const float* wv  = (const float*)d_in[5];
  const float* bv  = (const float*)d_in[6];
  const float* gam = (const float*)d_in[7];
  float* out = (float*)d_out;

  float* WT    = (float*)d_ws;                        // 2*64*32 = 4096 floats
  float* partE = WT + 4096;                           // 4*288*256 floats
  float* heat  = partE + (size_t)B_ * NCHUNK_ * 256;  // 4*256 floats

  k_prep   <<<1, 256, 0, stream>>>(wq, wk, WT);
  k_energy <<<dim3(NCHUNK_, B_), 512, 0, stream>>>(x, WT, bq, bk, partE);
  k_softmax<<<dim3(B_),          256, 0, stream>>>(partE, heat);
  k_mix    <<<dim3(HW_ / 16, B_), 256, 0, stream>>>(x, heat, wv, bv, gam, out);
}

// Round 4
// 242.260 us; speedup vs baseline: 1.4725x; 1.4725x over previous
//
#include <hip/hip_runtime.h>
#include <math.h>

#define B_  4
#define T_  16
#define C_  64
#define CQ_ 8
#define HW_ 9216          // 96*96
#define NCHUNK_ 288       // HW_/32

// ws layout (floats): WT[2][64][32] @ 0 ; partE @ 4096 ; heat @ 4096 + B*288*256

// ---------------------------------------------------------------------------
// k_prep: transpose conv weights so each ci's row (8 cq x 3 taps = 24 floats)
// is contiguous (stride 32) -> enables scalar (s_load) fetches in k_energy.
// ---------------------------------------------------------------------------
__global__ __launch_bounds__(256)
void k_prep(const float* __restrict__ wq, const float* __restrict__ wk,
            float* __restrict__ WT) {
  for (int j = threadIdx.x; j < CQ_ * C_ * 3; j += 256) {
    int ci = j / 24, r = j % 24;      // r = cqi*3 + d
    int cqi = r / 3, d = r % 3;
    WT[ci * 32 + r]        = wq[(cqi * C_ + ci) * 3 + d];
    WT[2048 + ci * 32 + r] = wk[(cqi * C_ + ci) * 3 + d];
  }
}

// ---------------------------------------------------------------------------
// k_energy: partial energies. grid (288, 4), block 512 = (t=16 x g=32).
// Conv weights come from global via wave-uniform (scalar) loads — no LDS.
// ---------------------------------------------------------------------------
__global__ __launch_bounds__(512, 4)
void k_energy(const float* __restrict__ x, const float* __restrict__ WT,
              const float* __restrict__ bq, const float* __restrict__ bk,
              float* __restrict__ partE) {
  // Q/K layout: [g][t][12], per-g stride 196 (breaks 16*12%32==0 bank cycle)
  __shared__ __attribute__((aligned(16))) float QK[2 * 32 * 196];
  __shared__ float Etmp[256];

  const int b   = blockIdx.y;
  const int hw0 = blockIdx.x * 32;
  const int tid = threadIdx.x;
  const int t = tid >> 5;   // 0..15
  const int g = tid & 31;   // 0..31
  const float* xb  = x + (size_t)(b * T_ * C_) * HW_ + hw0 + g;
  const float* wqt = WT;           // [ci*32 + cqi*3 + d]
  const float* wkt = WT + 2048;

  float qa[CQ_], ka[CQ_];
#pragma unroll
  for (int j = 0; j < CQ_; ++j) { qa[j] = 0.f; ka[j] = 0.f; }

#pragma unroll 2
  for (int ci = 0; ci < C_; ++ci) {
    float xm = 0.f, xp = 0.f;
    if (t > 0)      xm = xb[(size_t)((t - 1) * C_ + ci) * HW_];
    float x0 =           xb[(size_t)(t * C_ + ci) * HW_];
    if (t < T_ - 1) xp = xb[(size_t)((t + 1) * C_ + ci) * HW_];
    const float* wq_r = &wqt[ci * 32];
    const float* wk_r = &wkt[ci * 32];
#pragma unroll
    for (int j = 0; j < CQ_; ++j) {
      qa[j] += wq_r[j * 3 + 0] * xm + wq_r[j * 3 + 1] * x0 + wq_r[j * 3 + 2] * xp;
      ka[j] += wk_r[j * 3 + 0] * xm + wk_r[j * 3 + 1] * x0 + wk_r[j * 3 + 2] * xp;
    }
  }
#pragma unroll
  for (int j = 0; j < CQ_; ++j) { qa[j] += bq[j]; ka[j] += bk[j]; }

  float* Qs = &QK[0];
  float* Ks = &QK[32 * 196];
#pragma unroll
  for (int j = 0; j < CQ_; ++j) {
    Qs[g * 196 + t * 12 + j] = qa[j];
    Ks[g * 196 + t * 12 + j] = ka[j];
  }
  __syncthreads();

  // E-dot: thread -> (h, tt, ss); h splits the 32 g's in half.
  const int h  = tid >> 8;
  const int tt = (tid >> 4) & 15;
  const int ss = tid & 15;
  float e = 0.f;
  for (int gg = h * 16; gg < h * 16 + 16; ++gg) {
    const float4 q0 = *(const float4*)&Qs[gg * 196 + tt * 12];
    const float4 q1 = *(const float4*)&Qs[gg * 196 + tt * 12 + 4];
    const float4 k0 = *(const float4*)&Ks[gg * 196 + ss * 12];
    const float4 k1 = *(const float4*)&Ks[gg * 196 + ss * 12 + 4];
    e += q0.x * k0.x + q0.y * k0.y + q0.z * k0.z + q0.w * k0.w
       + q1.x * k1.x + q1.y * k1.y + q1.z * k1.z + q1.w * k1.w;
  }
  if (h == 1) Etmp[tt * 16 + ss] = e;
  __syncthreads();
  if (h == 0) {
    e += Etmp[tt * 16 + ss];
    partE[((size_t)(b * NCHUNK_ + blockIdx.x)) * 256 + tt * 16 + ss] = e;
  }
}

// ---------------------------------------------------------------------------
// k_softmax: reduce 288 partials and softmax over s. grid 4, block 256.
// ---------------------------------------------------------------------------
__global__ __launch_bounds__(256)
void k_softmax(const float* __restrict__ partE, float* __restrict__ heat) {
  const int b = blockIdx.x;
  const int tid = threadIdx.x;
  float e = 0.f;
  for (int ch = 0; ch < NCHUNK_; ++ch)
    e += partE[((size_t)(b * NCHUNK_ + ch)) * 256 + tid];
  float mx = e;
#pragma unroll
  for (int m = 1; m < 16; m <<= 1) mx = fmaxf(mx, __shfl_xor(mx, m, 64));
  float ex = expf(e - mx);
  float sm = ex;
#pragma unroll
  for (int m = 1; m < 16; m <<= 1) sm += __shfl_xor(sm, m, 64);
  heat[b * 256 + tid] = ex / sm;
}

// ---------------------------------------------------------------------------
// k_mix: fused tmix + cmix + residual, s-split into two staged phases.
//   out[b,t,c,g] = gamma*( sum_ci Wv[c,ci] * sum_s heat[t,s] x[b,s,ci,g]
//                          + bv[c] ) + x[b,t,c,g]
// grid (576, 4), block 256 = (t=16 x g=16).
// vs round 3: (a) __launch_bounds__(256,3) — VGPR cap ~170, NO spill (round-3
// forced 64 VGPR -> xh spilled to scratch, the regression); (b) single exit
// path, residual from global (staging just fetched those lines -> L2 hit);
// (c) c-mix computes 4 channels at once with 4 independent accumulators —
// breaks the 64-deep single-accumulator FMA dependency chain that capped
// VALUBusy at ~39%.
// ---------------------------------------------------------------------------
__global__ __launch_bounds__(256, 3)
void k_mix(const float* __restrict__ x, const float* __restrict__ heat,
           const float* __restrict__ wv, const float* __restrict__ bv,
           const float* __restrict__ gam, float* __restrict__ out) {
  __shared__ __attribute__((aligned(16))) float xs[8 * 16 * 68]; // [s'][g][ci]
  __shared__ float hs[256];

  const int b   = blockIdx.y;
  const int hw0 = blockIdx.x * 16;
  const int tid = threadIdx.x;

  hs[tid] = heat[b * 256 + tid];

  const float* xbase = x + (size_t)(b * T_ * C_) * HW_ + hw0;
  const int t = tid >> 4;   // 0..15
  const int g = tid & 15;   // 0..15

  float xh[C_];
#pragma unroll
  for (int ci = 0; ci < C_; ++ci) xh[ci] = 0.f;

#pragma unroll
  for (int p = 0; p < 2; ++p) {
    __syncthreads();   // protect xs (phase 0: hs write; phase 1: reuse)
    // stage x[b, p*8..p*8+7, :, hw0:hw0+16] -> xs[s'][g][ci]
#pragma unroll
    for (int kk = 0; kk < 8; ++kk) {
      int slot = kk * 256 + tid;        // 0..2047
      int row  = slot >> 2;             // s'*64 + ci
      int quad = slot & 3;              // which 4 g's
      int sp = row >> 6, ci = row & 63;
      float4 v = *(const float4*)(xbase +
                  (size_t)((p * 8 + sp) * C_ + ci) * HW_ + quad * 4);
      float* dst = &xs[(sp * 16 + quad * 4) * 68 + ci];
      dst[0 * 68] = v.x;
      dst[1 * 68] = v.y;
      dst[2 * 68] = v.z;
      dst[3 * 68] = v.w;
    }
    __syncthreads();

    float hp[8];
#pragma unroll
    for (int sp = 0; sp < 8; ++sp) hp[sp] = hs[t * 16 + p * 8 + sp];

    // xh[ci] += sum_{s'} hp[s'] * x[p*8+s', ci, g]
#pragma unroll
    for (int cq = 0; cq < 16; ++cq) {
      float ax = 0.f, ay = 0.f, az = 0.f, aw = 0.f;
#pragma unroll
      for (int sp = 0; sp < 8; ++sp) {
        const float4 v = *(const float4*)&xs[(sp * 16 + g) * 68 + cq * 4];
        ax += hp[sp] * v.x; ay += hp[sp] * v.y;
        az += hp[sp] * v.z; aw += hp[sp] * v.w;
      }
      xh[cq * 4 + 0] += ax; xh[cq * 4 + 1] += ay;
      xh[cq * 4 + 2] += az; xh[cq * 4 + 3] += aw;
    }
  }

  // c-mix: 4 channels per iteration, independent accumulators (ILP=4).
  // Weights wave-uniform -> s_load; residual from global (L2-hot).
  const float gamma = gam[0];
  const float* xr = x   + ((size_t)(b * T_ + t) * C_) * HW_ + hw0 + g;
  float*       op = out + ((size_t)(b * T_ + t) * C_) * HW_ + hw0 + g;
  for (int c4 = 0; c4 < 16; ++c4) {
    const float* w0 = wv + (c4 * 4 + 0) * C_;
    const float* w1 = wv + (c4 * 4 + 1) * C_;
    const float* w2 = wv + (c4 * 4 + 2) * C_;
    const float* w3 = wv + (c4 * 4 + 3) * C_;
    // issue residual loads early; FMAs below hide their latency
    float r0 = xr[(size_t)(c4 * 4 + 0) * HW_];
    float r1 = xr[(size_t)(c4 * 4 + 1) * HW_];
    float r2 = xr[(size_t)(c4 * 4 + 2) * HW_];
    float r3 = xr[(size_t)(c4 * 4 + 3) * HW_];
    float o0 = 0.f, o1 = 0.f, o2 = 0.f, o3 = 0.f;
#pragma unroll
    for (int ci = 0; ci < C_; ++ci) {
      const float xv = xh[ci];
      o0 += w0[ci] * xv; o1 += w1[ci] * xv;
      o2 += w2[ci] * xv; o3 += w3[ci] * xv;
    }
    op[(size_t)(c4 * 4 + 0) * HW_] = gamma * (o0 + bv[c4 * 4 + 0]) + r0;
    op[(size_t)(c4 * 4 + 1) * HW_] = gamma * (o1 + bv[c4 * 4 + 1]) + r1;
    op[(size_t)(c4 * 4 + 2) * HW_] = gamma * (o2 + bv[c4 * 4 + 2]) + r2;
    op[(size_t)(c4 * 4 + 3) * HW_] = gamma * (o3 + bv[c4 * 4 + 3]) + r3;
  }
}

// ---------------------------------------------------------------------------
extern "C" void kernel_launch(void* const* d_in, const int* in_sizes, int n_in,
                              void* d_out, int out_size, void* d_ws, size_t ws_size,
                              hipStream_t stream) {
  const float* x   = (const float*)d_in[0];
  const float* wq  = (const float*)d_in[1];
  const float* bq  = (const float*)d_in[2];
  const float* wk  = (const float*)d_in[3];
  const float* bk  = (const float*)d_in[4];
  const float* wv  = (const float*)d_in[5];
  const float* bv  = (const float*)d_in[6];
  const float* gam = (const float*)d_in[7];
  float* out = (float*)d_out;

  float* WT    = (float*)d_ws;                        // 2*64*32 = 4096 floats
  float* partE = WT + 4096;                           // 4*288*256 floats
  float* heat  = partE + (size_t)B_ * NCHUNK_ * 256;  // 4*256 floats

  k_prep   <<<1, 256, 0, stream>>>(wq, wk, WT);
  k_energy <<<dim3(NCHUNK_, B_), 512, 0, stream>>>(x, WT, bq, bk, partE);
  k_softmax<<<dim3(B_),          256, 0, stream>>>(partE, heat);
  k_mix    <<<dim3(HW_ / 16, B_), 256, 0, stream>>>(x, heat, wv, bv, gam, out);
}

// Round 5
// 215.314 us; speedup vs baseline: 1.6568x; 1.1251x over previous
//
#include <hip/hip_runtime.h>
#include <math.h>

#define B_  4
#define T_  16
#define C_  64
#define CQ_ 8
#define HW_ 9216          // 96*96
#define NCHUNK_ 288       // HW_/32

typedef __attribute__((ext_vector_type(8))) short  s16x8;  // 8 bf16 = 4 VGPR
typedef __attribute__((ext_vector_type(4))) short  s16x4;
typedef __attribute__((ext_vector_type(4))) float  f32x4;

static __device__ __forceinline__ short f2bf(float f) {
  union { float f; unsigned u; } v; v.f = f;
  return (short)((v.u + 0x7FFFu + ((v.u >> 16) & 1u)) >> 16);  // RNE
}

// ---------------------------------------------------------------------------
// k_prep: transpose conv weights so each ci's row (8 cq x 3 taps = 24 floats)
// is contiguous (stride 32) -> enables scalar (s_load) fetches in k_energy.
// ---------------------------------------------------------------------------
__global__ __launch_bounds__(256)
void k_prep(const float* __restrict__ wq, const float* __restrict__ wk,
            float* __restrict__ WT) {
  for (int j = threadIdx.x; j < CQ_ * C_ * 3; j += 256) {
    int ci = j / 24, r = j % 24;      // r = cqi*3 + d
    int cqi = r / 3, d = r % 3;
    WT[ci * 32 + r]        = wq[(cqi * C_ + ci) * 3 + d];
    WT[2048 + ci * 32 + r] = wk[(cqi * C_ + ci) * 3 + d];
  }
}

// ---------------------------------------------------------------------------
// k_energy: partial energies. grid (288, 4), block 512 = (t=16 x g=32).
// (unchanged from round 4 — next round's target)
// ---------------------------------------------------------------------------
__global__ __launch_bounds__(512, 4)
void k_energy(const float* __restrict__ x, const float* __restrict__ WT,
              const float* __restrict__ bq, const float* __restrict__ bk,
              float* __restrict__ partE) {
  __shared__ __attribute__((aligned(16))) float QK[2 * 32 * 196];
  __shared__ float Etmp[256];

  const int b   = blockIdx.y;
  const int hw0 = blockIdx.x * 32;
  const int tid = threadIdx.x;
  const int t = tid >> 5;   // 0..15
  const int g = tid & 31;   // 0..31
  const float* xb  = x + (size_t)(b * T_ * C_) * HW_ + hw0 + g;
  const float* wqt = WT;           // [ci*32 + cqi*3 + d]
  const float* wkt = WT + 2048;

  float qa[CQ_], ka[CQ_];
#pragma unroll
  for (int j = 0; j < CQ_; ++j) { qa[j] = 0.f; ka[j] = 0.f; }

#pragma unroll 2
  for (int ci = 0; ci < C_; ++ci) {
    float xm = 0.f, xp = 0.f;
    if (t > 0)      xm = xb[(size_t)((t - 1) * C_ + ci) * HW_];
    float x0 =           xb[(size_t)(t * C_ + ci) * HW_];
    if (t < T_ - 1) xp = xb[(size_t)((t + 1) * C_ + ci) * HW_];
    const float* wq_r = &wqt[ci * 32];
    const float* wk_r = &wkt[ci * 32];
#pragma unroll
    for (int j = 0; j < CQ_; ++j) {
      qa[j] += wq_r[j * 3 + 0] * xm + wq_r[j * 3 + 1] * x0 + wq_r[j * 3 + 2] * xp;
      ka[j] += wk_r[j * 3 + 0] * xm + wk_r[j * 3 + 1] * x0 + wk_r[j * 3 + 2] * xp;
    }
  }
#pragma unroll
  for (int j = 0; j < CQ_; ++j) { qa[j] += bq[j]; ka[j] += bk[j]; }

  float* Qs = &QK[0];
  float* Ks = &QK[32 * 196];
#pragma unroll
  for (int j = 0; j < CQ_; ++j) {
    Qs[g * 196 + t * 12 + j] = qa[j];
    Ks[g * 196 + t * 12 + j] = ka[j];
  }
  __syncthreads();

  const int h  = tid >> 8;
  const int tt = (tid >> 4) & 15;
  const int ss = tid & 15;
  float e = 0.f;
  for (int gg = h * 16; gg < h * 16 + 16; ++gg) {
    const float4 q0 = *(const float4*)&Qs[gg * 196 + tt * 12];
    const float4 q1 = *(const float4*)&Qs[gg * 196 + tt * 12 + 4];
    const float4 k0 = *(const float4*)&Ks[gg * 196 + ss * 12];
    const float4 k1 = *(const float4*)&Ks[gg * 196 + ss * 12 + 4];
    e += q0.x * k0.x + q0.y * k0.y + q0.z * k0.z + q0.w * k0.w
       + q1.x * k1.x + q1.y * k1.y + q1.z * k1.z + q1.w * k1.w;
  }
  if (h == 1) Etmp[tt * 16 + ss] = e;
  __syncthreads();
  if (h == 0) {
    e += Etmp[tt * 16 + ss];
    partE[((size_t)(b * NCHUNK_ + blockIdx.x)) * 256 + tt * 16 + ss] = e;
  }
}

// ---------------------------------------------------------------------------
// k_softmax: reduce 288 partials and softmax over s. grid 4, block 256.
// ---------------------------------------------------------------------------
__global__ __launch_bounds__(256)
void k_softmax(const float* __restrict__ partE, float* __restrict__ heat) {
  const int b = blockIdx.x;
  const int tid = threadIdx.x;
  float e = 0.f;
  for (int ch = 0; ch < NCHUNK_; ++ch)
    e += partE[((size_t)(b * NCHUNK_ + ch)) * 256 + tid];
  float mx = e;
#pragma unroll
  for (int m = 1; m < 16; m <<= 1) mx = fmaxf(mx, __shfl_xor(mx, m, 64));
  float ex = expf(e - mx);
  float sm = ex;
#pragma unroll
  for (int m = 1; m < 16; m <<= 1) sm += __shfl_xor(sm, m, 64);
  heat[b * 256 + tid] = ex / sm;
}

// ---------------------------------------------------------------------------
// k_mix (MFMA): per block (b, 16-g tile): out = gamma*(Wv @ (heat @ X)) + bias
// + residual.  Two chained mfma_f32_16x16x32_bf16 GEMMs:
//   GEMM1: xh[t,(ci,g)] = heat(16x16,K pad 32) @ X(16x1024)   [64 MFMA/block]
//   GEMM2: out[c,(t,g)] = Wv(64x64) @ xh(64x256)              [128 MFMA/block]
// LDS union (48 KB -> 3 blocks/CU):
//   phase A: xs bf16, row = ci*16+g (stride 24 sh), elem s stored at
//            s ^ (2*(ci&7))  (XOR swizzle kills the 16-way staging-write
//            conflict from the row-stride-16 pattern; reads use b32 pairs)
//   phase B: xh bf16, row = n = t*16+g (stride 72 sh), ci contiguous ->
//            b128 B-fragment reads, 2-way banks (72*2B stride)
// k-packing assumption (lane k = (lane>>4)*8+j) is used consistently for A
// and B in each GEMM, so any hidden k-permutation cancels; C/D layout is the
// m89-verified col=lane&15 / row=(lane>>4)*4+reg.
// ---------------------------------------------------------------------------
__global__ __launch_bounds__(256, 3)
void k_mix(const float* __restrict__ x, const float* __restrict__ heat,
           const float* __restrict__ wv, const float* __restrict__ bv,
           const float* __restrict__ gam, float* __restrict__ out) {
  __shared__ __attribute__((aligned(16))) short sm[24576];  // 48 KB union

  const int b    = blockIdx.y;
  const int hw0  = blockIdx.x * 16;
  const int tid  = threadIdx.x;
  const int lane = tid & 63;
  const int w    = tid >> 6;      // wave 0..3
  const int l15  = lane & 15;
  const int lq   = lane >> 4;     // quarter 0..3

  union U8 { s16x8 v; int i[4]; };
  const f32x4 fz = {0.f, 0.f, 0.f, 0.f};

  // ---- stage x tile -> bf16 xs -------------------------------------------
  {
    const int ci = tid >> 2, q = tid & 3;
    const int sw = 2 * (ci & 7);
    const float* xp = x + ((size_t)b * T_ * C_ + ci) * HW_ + hw0 + q * 4;
    short* r0 = &sm[(ci * 16 + q * 4 + 0) * 24];
    short* r1 = r0 + 24; short* r2 = r0 + 48; short* r3 = r0 + 72;
#pragma unroll
    for (int s = 0; s < T_; ++s) {
      float4 v = *(const float4*)(xp + (size_t)s * C_ * HW_);
      const int sp = s ^ sw;
      r0[sp] = f2bf(v.x); r1[sp] = f2bf(v.y);
      r2[sp] = f2bf(v.z); r3[sp] = f2bf(v.w);
    }
  }

  // ---- A1 fragment: heat[t][s], K=16 zero-padded to 32 -------------------
  U8 ha; ha.i[0] = ha.i[1] = ha.i[2] = ha.i[3] = 0;
  if (lane < 32) {
    const float* hp = heat + b * 256 + l15 * 16 + lq * 8;
    float4 h0 = *(const float4*)hp;
    float4 h1 = *(const float4*)(hp + 4);
    ha.v[0] = f2bf(h0.x); ha.v[1] = f2bf(h0.y);
    ha.v[2] = f2bf(h0.z); ha.v[3] = f2bf(h0.w);
    ha.v[4] = f2bf(h1.x); ha.v[5] = f2bf(h1.y);
    ha.v[6] = f2bf(h1.z); ha.v[7] = f2bf(h1.w);
  }
  __syncthreads();

  // ---- GEMM1: 16 MFMAs, ci-tile = w*16+i ----------------------------------
  // c1[i]: lane holds xh[t=(lq*4+reg)][ci=w*16+i][g=l15]
  f32x4 c1[16];
#pragma unroll
  for (int i = 0; i < 16; ++i) {
    U8 bx; bx.i[0] = bx.i[1] = bx.i[2] = bx.i[3] = 0;
    if (lane < 32) {
      const int ci = w * 16 + i;
      const int rowb = (ci * 16 + l15) * 24;
      const int sw = 2 * (ci & 7);
      const int s0 = lq * 8;
#pragma unroll
      for (int m = 0; m < 4; ++m)
        bx.i[m] = *(const int*)&sm[rowb + ((s0 + 2 * m) ^ sw)];
    }
    c1[i] = __builtin_amdgcn_mfma_f32_16x16x32_bf16(ha.v, bx.v, fz, 0, 0, 0);
  }
  __syncthreads();   // all xs reads done; sm becomes xh

  // ---- write xh -> LDS [n=t*16+g][ci] (stride 72), bf16, b64 packs -------
#pragma unroll
  for (int r = 0; r < 4; ++r) {
    const int t = lq * 4 + r;
    short* dst = &sm[(t * 16 + l15) * 72 + w * 16];
#pragma unroll
    for (int q = 0; q < 4; ++q) {
      s16x4 pk;
      pk[0] = f2bf(c1[q * 4 + 0][r]); pk[1] = f2bf(c1[q * 4 + 1][r]);
      pk[2] = f2bf(c1[q * 4 + 2][r]); pk[3] = f2bf(c1[q * 4 + 3][r]);
      *(s16x4*)(dst + q * 4) = pk;
    }
  }

  // ---- A2 fragments: Wv (4 c-tiles x 2 k-steps) + bias + gamma -----------
  U8 a2[8];
#pragma unroll
  for (int ct = 0; ct < 4; ++ct)
#pragma unroll
    for (int ks = 0; ks < 2; ++ks) {
      const float* wp = wv + (ct * 16 + l15) * C_ + ks * 32 + lq * 8;
      float4 w0 = *(const float4*)wp;
      float4 w1 = *(const float4*)(wp + 4);
      U8 f;
      f.v[0] = f2bf(w0.x); f.v[1] = f2bf(w0.y);
      f.v[2] = f2bf(w0.z); f.v[3] = f2bf(w0.w);
      f.v[4] = f2bf(w1.x); f.v[5] = f2bf(w1.y);
      f.v[6] = f2bf(w1.z); f.v[7] = f2bf(w1.w);
      a2[ct * 2 + ks] = f;
    }
  f32x4 bvr[4];
#pragma unroll
  for (int ct = 0; ct < 4; ++ct)
    bvr[ct] = *(const f32x4*)(bv + ct * 16 + lq * 4);
  const float gamma = gam[0];
  __syncthreads();   // xh visible

  // ---- GEMM2 + epilogue: this wave owns t = w*4 .. w*4+3 ------------------
#pragma unroll
  for (int ntq = 0; ntq < 4; ++ntq) {
    const int t = w * 4 + ntq;
    const short* xr0 = &sm[(t * 16 + l15) * 72];
    s16x8 b0 = *(const s16x8*)(xr0 + lq * 8);        // k = ci   0..31 slice
    s16x8 b1 = *(const s16x8*)(xr0 + 32 + lq * 8);   // k = ci  32..63 slice
    const float* resp = x   + ((size_t)(b * T_ + t) * C_) * HW_ + hw0 + l15;
    float*       op   = out + ((size_t)(b * T_ + t) * C_) * HW_ + hw0 + l15;
#pragma unroll
    for (int ct = 0; ct < 4; ++ct) {
      f32x4 acc = __builtin_amdgcn_mfma_f32_16x16x32_bf16(a2[ct * 2 + 0].v, b0, fz, 0, 0, 0);
      acc = __builtin_amdgcn_mfma_f32_16x16x32_bf16(a2[ct * 2 + 1].v, b1, acc, 0, 0, 0);
      const int cb = ct * 16 + lq * 4;
#pragma unroll
      for (int r = 0; r < 4; ++r) {
        const size_t off = (size_t)(cb + r) * HW_;
        op[off] = gamma * (acc[r] + bvr[ct][r]) + resp[off];
      }
    }
  }
}

// ---------------------------------------------------------------------------
extern "C" void kernel_launch(void* const* d_in, const int* in_sizes, int n_in,
                              void* d_out, int out_size, void* d_ws, size_t ws_size,
                              hipStream_t stream) {
  const float* x   = (const float*)d_in[0];
  const float* wq  = (const float*)d_in[1];
  const float* bq  = (const float*)d_in[2];
  const float* wk  = (const float*)d_in[3];
  const float* bk  = (const float*)d_in[4];
  const float* wv  = (const float*)d_in[5];
  const float* bv  = (const float*)d_in[6];
  const float* gam = (const float*)d_in[7];
  float* out = (float*)d_out;

  float* WT    = (float*)d_ws;                        // 2*64*32 = 4096 floats
  float* partE = WT + 4096;                           // 4*288*256 floats
  float* heat  = partE + (size_t)B_ * NCHUNK_ * 256;  // 4*256 floats

  k_prep   <<<1, 256, 0, stream>>>(wq, wk, WT);
  k_energy <<<dim3(NCHUNK_, B_), 512, 0, stream>>>(x, WT, bq, bk, partE);
  k_softmax<<<dim3(B_),          256, 0, stream>>>(partE, heat);
  k_mix    <<<dim3(HW_ / 16, B_), 256, 0, stream>>>(x, heat, wv, bv, gam, out);
}